// Round 3
// baseline (282.632 us; speedup 1.0000x reference)
//
#include <hip/hip_runtime.h>

#define NT    85
#define BINS  28
#define NTB   (NT * BINS)      // 2380
#define TILE  128
#define MAXR  64               // max staged (tj,ti) LUT rows in LDS (64*28*8B = 14336 B)

// ---------------- LUT repack: pot[t1][t2][d] -> float2 (e[d], e[min(d+1,27)]) ----------------
__global__ void repack_lut_k(const float* __restrict__ pot, float2* __restrict__ lut) {
    int idx = blockIdx.x * blockDim.x + threadIdx.x;
    const int total = NT * NT * BINS;
    if (idx >= total) return;
    int d  = idx % BINS;
    int ab = idx / BINS;
    int d1 = (d + 1 < BINS) ? d + 1 : BINS - 1;
    lut[idx] = make_float2(pot[idx], pot[ab * BINS + d1]);
}

// ---------------- fused histogram + exclusive scan (one block, LDS hist) ----------------
__global__ __launch_bounds__(256) void hist_scan_k(const int* __restrict__ type,
                                                   int* __restrict__ offs, int N) {
    __shared__ int h[NT];
    for (int t = threadIdx.x; t < NT; t += 256) h[t] = 0;
    __syncthreads();
    for (int i = threadIdx.x; i < N; i += 256) atomicAdd(&h[type[i]], 1);
    __syncthreads();
    if (threadIdx.x == 0) {
        int s = 0;
        for (int t = 0; t < NT; ++t) { int c = h[t]; offs[t] = s; s += c; }
    }
}

// pack atom: (x, y, z, bits(type<<10 | res)); res < 1024, type < 128
__global__ void scatter_k(const float* __restrict__ coords, const int* __restrict__ res,
                          const int* __restrict__ type, int* __restrict__ offs,
                          float4* __restrict__ pc, int N) {
    int i = blockIdx.x * blockDim.x + threadIdx.x;
    if (i >= N) return;
    int t = type[i];
    int p = atomicAdd(&offs[t], 1);
    pc[p] = make_float4(coords[3 * i], coords[3 * i + 1], coords[3 * i + 2],
                        __int_as_float((t << 10) | res[i]));
}

// ---------------- main pair kernel ----------------
// Atoms are type-sorted, so each 128-tile spans a contiguous type window.
// Per block: stage the (tj,ti) sub-LUT rows into LDS; inner loop does LDS gathers only.
// DIAG=false: strict upper-triangle off-diagonal tiles. DIAG=true: diagonal tiles.
template <bool DIAG>
__global__ __launch_bounds__(256) void dfire_pairs_t(
    const float4* __restrict__ pc,
    const float2* __restrict__ lut,
    float* __restrict__ partial, int T) {

    __shared__ float4 jc[TILE];
    __shared__ float2 sublut[MAXR * BINS];
    __shared__ float  wsum[4];

    int r, c;
    if (DIAG) {
        r = blockIdx.x; c = r;
    } else {
        // strict upper triangle: row r has (T-1-r) entries; prefix P(r) = r*(T-1) - r*(r-1)/2
        int k = blockIdx.x;
        double tm = 2.0 * T - 1.0;
        double disc = tm * tm - 8.0 * (double)k;
        if (disc < 0.0) disc = 0.0;
        r = (int)((tm - sqrt(disc)) * 0.5);
        if (r < 0) r = 0;
        if (r > T - 2) r = T - 2;
        while (r > 0 && (r * (T - 1) - r * (r - 1) / 2) > k) --r;
        while (((r + 1) * (T - 1) - (r + 1) * r / 2) <= k) ++r;
        c = r + 1 + (k - (r * (T - 1) - r * (r - 1) / 2));
    }

    int bi = r * TILE, bj = c * TILE;
    int tid = threadIdx.x;

    // contiguous type windows of the two tiles (atoms sorted by type)
    int tminI = __float_as_int(pc[bi].w) >> 10;
    int tmaxI = __float_as_int(pc[bi + TILE - 1].w) >> 10;
    int tminJ = __float_as_int(pc[bj].w) >> 10;
    int tmaxJ = __float_as_int(pc[bj + TILE - 1].w) >> 10;
    int nI = tmaxI - tminI + 1;
    int nRows = nI * (tmaxJ - tminJ + 1);
    bool useLds = (nRows <= MAXR);          // block-uniform

    if (tid < TILE) {
        float4 cj = pc[bj + tid];
        if (useLds) {
            // repack w: bits[0..9]=res, bits[10..]=element offset (tj-tminJ)*nI*BINS
            int wj = __float_as_int(cj.w);
            int jrow = ((wj >> 10) - tminJ) * nI * BINS;   // < MAXR*BINS = 1792
            cj.w = __int_as_float((jrow << 10) | (wj & 1023));
        }
        jc[tid] = cj;
    }
    if (useLds) {
        int tot = nRows * BINS;
        for (int x = tid; x < tot; x += 256) {
            int u   = x / BINS, d = x - u * BINS;
            int cjl = u / nI,  cil = u - cjl * nI;
            sublut[x] = lut[(tminJ + cjl) * NTB + (tminI + cil) * BINS + d];
        }
    }

    // each thread owns TWO i atoms (i0, i0+64) and 32 j's at stride 4
    int i0 = tid & 63;
    int i1 = i0 + 64;
    float4 ciA = pc[bi + i0];
    float4 ciB = pc[bi + i1];
    int wA = __float_as_int(ciA.w);
    int wB = __float_as_int(ciB.w);
    int iresA = wA & 1023;
    int iresB = wB & 1023;
    int rowA, rowB;    // LDS path: (ti-tminI)*BINS element offset; global path: ti*BINS
    if (useLds) { rowA = ((wA >> 10) - tminI) * BINS; rowB = ((wB >> 10) - tminI) * BINS; }
    else        { rowA = (wA >> 10) * BINS;           rowB = (wB >> 10) * BINS; }
    __syncthreads();

    float a0 = 0.f, a1 = 0.f, a2 = 0.f, a3 = 0.f;
    float b0 = 0.f, b1 = 0.f, b2 = 0.f, b3 = 0.f;

#define PAIR_BODY(E_EXPR, CI, IRES, ROW, IEFF, ACC) do {               \
    float dx = CI.x - cj.x, dy = CI.y - cj.y, dz = CI.z - cj.z;        \
    float d2 = fmaf(dx, dx, fmaf(dy, dy, dz * dz));                    \
    int  sep = abs(IRES - jres);                                       \
    bool v = (sep > 2) & (d2 < 19.6f * 19.6f);                         \
    if (DIAG) v = v & (J > IEFF);                                      \
    float ds    = __builtin_amdgcn_sqrtf(d2) * (1.0f / 0.7f);          \
    float dsc   = fminf(ds, 27.0f);                                    \
    int   d0    = (int)dsc;                                            \
    float alpha = ds - (float)d0;                                      \
    float2 e = (E_EXPR);                                               \
    float en = fmaf(alpha, e.y - e.x, e.x);                            \
    ACC = fmaf(v ? 1.0f : 0.0f, en, ACC);                              \
} while (0)

    if (useLds) {
        int jj = tid >> 6;   // 0..3: wave-uniform j group (LDS broadcast preserved)
#define STEP2L(JX, AA, AB) do {                                        \
    const int J = (JX);                                                \
    float4 cj = jc[J];                                                 \
    int   wj   = __float_as_int(cj.w);                                 \
    int   jres = wj & 1023;                                            \
    int   jrow = wj >> 10;                                             \
    PAIR_BODY(sublut[jrow + rowA + d0], ciA, iresA, rowA, i0, AA);     \
    PAIR_BODY(sublut[jrow + rowB + d0], ciB, iresB, rowB, i1, AB);     \
} while (0)
        #pragma unroll
        for (int s = 0; s < 4; ++s, jj += 32) {
            STEP2L(jj,      a0, b0);
            STEP2L(jj + 4,  a1, b1);
            STEP2L(jj + 8,  a2, b2);
            STEP2L(jj + 12, a3, b3);
            STEP2L(jj + 16, a0, b0);
            STEP2L(jj + 20, a1, b1);
            STEP2L(jj + 24, a2, b2);
            STEP2L(jj + 28, a3, b3);
        }
#undef STEP2L
    } else {
        int jj = tid >> 6;
#define STEP2G(JX, AA, AB) do {                                        \
    const int J = (JX);                                                \
    float4 cj = jc[J];                                                 \
    int   wj   = __float_as_int(cj.w);                                 \
    int   jres = wj & 1023;                                            \
    int   tjb  = (wj >> 10) * NTB;                                     \
    PAIR_BODY(lut[tjb + rowA + d0], ciA, iresA, rowA, i0, AA);         \
    PAIR_BODY(lut[tjb + rowB + d0], ciB, iresB, rowB, i1, AB);         \
} while (0)
        #pragma unroll
        for (int s = 0; s < 4; ++s, jj += 32) {
            STEP2G(jj,      a0, b0);
            STEP2G(jj + 4,  a1, b1);
            STEP2G(jj + 8,  a2, b2);
            STEP2G(jj + 12, a3, b3);
            STEP2G(jj + 16, a0, b0);
            STEP2G(jj + 20, a1, b1);
            STEP2G(jj + 24, a2, b2);
            STEP2G(jj + 28, a3, b3);
        }
#undef STEP2G
    }
#undef PAIR_BODY

    float acc = ((a0 + a1) + (a2 + a3)) + ((b0 + b1) + (b2 + b3));
    for (int off = 32; off > 0; off >>= 1)
        acc += __shfl_down(acc, off, 64);
    if ((tid & 63) == 0) wsum[tid >> 6] = acc;
    __syncthreads();
    if (tid == 0) partial[blockIdx.x] = (wsum[0] + wsum[1]) + (wsum[2] + wsum[3]);
}

// ---------------- final reduction of per-block partials -> out[0] ----------------
__global__ __launch_bounds__(256) void reduce_k(const float* __restrict__ p, int n,
                                                float* __restrict__ out) {
    __shared__ float ws[4];
    float a = 0.f;
    for (int i = threadIdx.x; i < n; i += 256) a += p[i];
    for (int off = 32; off > 0; off >>= 1)
        a += __shfl_down(a, off, 64);
    if ((threadIdx.x & 63) == 0) ws[threadIdx.x >> 6] = a;
    __syncthreads();
    if (threadIdx.x == 0) out[0] = (ws[0] + ws[1]) + (ws[2] + ws[3]);
}

// ---------------- fallback (ws too small): unsorted, direct pot reads, atomics ----------------
__global__ __launch_bounds__(256) void dfire_pairs_fb(
    const float* __restrict__ coords, const int* __restrict__ res,
    const int* __restrict__ type, const float* __restrict__ pot,
    float* __restrict__ out, int T) {

    __shared__ float jx[TILE], jy[TILE], jz[TILE];
    __shared__ int   jres[TILE], jtype[TILE];

    int k = blockIdx.x;
    int r = (int)((2.0 * T + 1.0 - sqrt((2.0 * T + 1.0) * (2.0 * T + 1.0) - 8.0 * (double)k)) * 0.5);
    if (r < 0) r = 0;
    if (r > T - 1) r = T - 1;
    while (r > 0 && (r * T - r * (r - 1) / 2) > k) --r;
    while (((r + 1) * T - (r + 1) * r / 2) <= k) ++r;
    int c = r + (k - (r * T - r * (r - 1) / 2));

    int bi = r * TILE, bj = c * TILE;
    int tid = threadIdx.x;
    if (tid < TILE) {
        int gj = bj + tid;
        jx[tid] = coords[3 * gj]; jy[tid] = coords[3 * gj + 1]; jz[tid] = coords[3 * gj + 2];
        jres[tid] = res[gj]; jtype[tid] = type[gj];
    }
    int ii = tid & (TILE - 1);
    int gi = bi + ii;
    float ix = coords[3 * gi], iy = coords[3 * gi + 1], iz = coords[3 * gi + 2];
    int ires = res[gi], it = type[gi];
    int ii_eff = (bi == bj) ? ii : -1;
    __syncthreads();

    float acc = 0.f;
    int jj = tid >> 7;
    for (int s = 0; s < TILE / 2; ++s, jj += 2) {
        float dx = ix - jx[jj], dy = iy - jy[jj], dz = iz - jz[jj];
        float d2 = dx * dx + dy * dy + dz * dz;
        float dist = sqrtf(d2) + 1e-8f;
        int sep = abs(ires - jres[jj]);
        bool v = (sep > 2) & (dist < 19.6f) & (jj > ii_eff);
        if (v) {
            float ds = dist * (1.0f / 0.7f);
            int d0 = (int)fminf(ds, 27.0f);
            int d1 = (d0 + 1 < BINS) ? d0 + 1 : BINS - 1;
            float alpha = ds - (float)d0;
            int row = (jtype[jj] * NT + it) * BINS;
            float e0 = pot[row + d0], e1 = pot[row + d1];
            acc += e0 + alpha * (e1 - e0);
        }
    }
    for (int off = 32; off > 0; off >>= 1)
        acc += __shfl_down(acc, off, 64);
    if ((tid & 63) == 0) atomicAdd(out, acc);
}

extern "C" void kernel_launch(void* const* d_in, const int* in_sizes, int n_in,
                              void* d_out, int out_size, void* d_ws, size_t ws_size,
                              hipStream_t stream) {
    const float* coords = (const float*)d_in[0];
    const float* pot    = (const float*)d_in[1];
    const int*   res    = (const int*)d_in[2];
    const int*   type   = (const int*)d_in[3];
    // d_in[4], d_in[5] (i_idx/j_idx) unused: pairs generated on the fly from triu structure.

    const int N = in_sizes[2];
    const int T = N / TILE;
    const int nblk = T * (T + 1) / 2;

    float* out = (float*)d_out;

    const size_t lutBytes  = (size_t)NT * NT * BINS * sizeof(float2);   // 1,618,400 (16B-aligned)
    const size_t pcBytes   = (size_t)N * sizeof(float4);
    const size_t offsBytes = 128 * sizeof(int);
    const size_t partBytes = (size_t)nblk * sizeof(float);
    const size_t need = lutBytes + pcBytes + offsBytes + partBytes;

    if (ws_size >= need) {
        char* w = (char*)d_ws;
        float2* lut     = (float2*)w;                     w += lutBytes;
        float4* pc      = (float4*)w;                     w += pcBytes;
        int*    offs    = (int*)w;                        w += offsBytes;
        float*  partial = (float*)w;

        const int total = NT * NT * BINS;
        const int nOff  = T * (T - 1) / 2;   // off-diagonal tiles
        repack_lut_k<<<(total + 255) / 256, 256, 0, stream>>>(pot, lut);
        hist_scan_k<<<1, 256, 0, stream>>>(type, offs, N);
        scatter_k<<<(N + 255) / 256, 256, 0, stream>>>(coords, res, type, offs, pc, N);
        dfire_pairs_t<false><<<nOff, 256, 0, stream>>>(pc, lut, partial, T);
        dfire_pairs_t<true><<<T, 256, 0, stream>>>(pc, lut, partial + nOff, T);
        reduce_k<<<1, 256, 0, stream>>>(partial, nOff + T, out);
    } else {
        hipMemsetAsync(out, 0, sizeof(float), stream);
        dfire_pairs_fb<<<nblk, 256, 0, stream>>>(coords, res, type, pot, out, T);
    }
}

// Round 4
// 282.434 us; speedup vs baseline: 1.0007x; 1.0007x over previous
//
#include <hip/hip_runtime.h>

#define NT    85
#define BINS  28
#define NTB   (NT * BINS)      // 2380
#define TILE  128
#define MAXR  64               // max staged (tj,ti) LUT rows in LDS (64*28*8B = 14336 B)
#define RB    ((NT * NT * BINS + 255) / 256)   // 791 repack blocks

// ---------------- prep: repack LUT (blocks 0..RB-1)  +  hist/scan + out=0 (block RB) ----------------
__global__ __launch_bounds__(256) void prep_k(const float* __restrict__ pot,
                                              float2* __restrict__ lut,
                                              const int* __restrict__ type,
                                              int* __restrict__ offs,
                                              float* __restrict__ out, int N) {
    const int total = NT * NT * BINS;
    if (blockIdx.x < RB) {
        int idx = blockIdx.x * 256 + threadIdx.x;
        if (idx < total) {
            int d  = idx % BINS;
            int ab = idx / BINS;
            int d1 = (d + 1 < BINS) ? d + 1 : BINS - 1;
            lut[idx] = make_float2(pot[idx], pot[ab * BINS + d1]);
        }
    } else {
        __shared__ int h[NT];
        for (int t = threadIdx.x; t < NT; t += 256) h[t] = 0;
        __syncthreads();
        for (int i = threadIdx.x; i < N; i += 256) atomicAdd(&h[type[i]], 1);
        __syncthreads();
        if (threadIdx.x == 0) {
            int s = 0;
            for (int t = 0; t < NT; ++t) { int c = h[t]; offs[t] = s; s += c; }
            out[0] = 0.0f;
        }
    }
}

// pack atom: (x, y, z, bits(type<<10 | res)); res < 1024, type < 128
__global__ void scatter_k(const float* __restrict__ coords, const int* __restrict__ res,
                          const int* __restrict__ type, int* __restrict__ offs,
                          float4* __restrict__ pc, int N) {
    int i = blockIdx.x * blockDim.x + threadIdx.x;
    if (i >= N) return;
    int t = type[i];
    int p = atomicAdd(&offs[t], 1);
    pc[p] = make_float4(coords[3 * i], coords[3 * i + 1], coords[3 * i + 2],
                        __int_as_float((t << 10) | res[i]));
}

// ---------------- main pair kernel ----------------
// Atoms are type-sorted, so each 128-tile spans a contiguous type window.
// Per block: stage the (tj,ti) sub-LUT rows into LDS; inner loop does LDS gathers only.
// Epilogue: one float atomicAdd per block into out[0] (no partials / reduce kernel).
// DIAG=false: strict upper-triangle off-diagonal tiles. DIAG=true: diagonal tiles.
template <bool DIAG>
__global__ __launch_bounds__(256) void dfire_pairs_t(
    const float4* __restrict__ pc,
    const float2* __restrict__ lut,
    float* __restrict__ out, int T) {

    __shared__ float4 jc[TILE];
    __shared__ float2 sublut[MAXR * BINS];
    __shared__ float  wsum[4];

    int r, c;
    if (DIAG) {
        r = blockIdx.x; c = r;
    } else {
        // strict upper triangle: row r has (T-1-r) entries; prefix P(r) = r*(T-1) - r*(r-1)/2
        int k = blockIdx.x;
        double tm = 2.0 * T - 1.0;
        double disc = tm * tm - 8.0 * (double)k;
        if (disc < 0.0) disc = 0.0;
        r = (int)((tm - sqrt(disc)) * 0.5);
        if (r < 0) r = 0;
        if (r > T - 2) r = T - 2;
        while (r > 0 && (r * (T - 1) - r * (r - 1) / 2) > k) --r;
        while (((r + 1) * (T - 1) - (r + 1) * r / 2) <= k) ++r;
        c = r + 1 + (k - (r * (T - 1) - r * (r - 1) / 2));
    }

    int bi = r * TILE, bj = c * TILE;
    int tid = threadIdx.x;

    // contiguous type windows of the two tiles (atoms sorted by type)
    int tminI = __float_as_int(pc[bi].w) >> 10;
    int tmaxI = __float_as_int(pc[bi + TILE - 1].w) >> 10;
    int tminJ = __float_as_int(pc[bj].w) >> 10;
    int tmaxJ = __float_as_int(pc[bj + TILE - 1].w) >> 10;
    int nI = tmaxI - tminI + 1;
    int nRows = nI * (tmaxJ - tminJ + 1);
    bool useLds = (nRows <= MAXR);          // block-uniform

    if (tid < TILE) {
        float4 cj = pc[bj + tid];
        if (useLds) {
            // repack w: bits[0..9]=res, bits[10..]=element offset (tj-tminJ)*nI*BINS
            int wj = __float_as_int(cj.w);
            int jrow = ((wj >> 10) - tminJ) * nI * BINS;   // < MAXR*BINS = 1792
            cj.w = __int_as_float((jrow << 10) | (wj & 1023));
        }
        jc[tid] = cj;
    }
    if (useLds) {
        int tot = nRows * BINS;
        for (int x = tid; x < tot; x += 256) {
            int u   = x / BINS, d = x - u * BINS;
            int cjl = u / nI,  cil = u - cjl * nI;
            sublut[x] = lut[(tminJ + cjl) * NTB + (tminI + cil) * BINS + d];
        }
    }

    // each thread owns TWO i atoms (i0, i0+64) and 32 j's at stride 4
    int i0 = tid & 63;
    int i1 = i0 + 64;
    float4 ciA = pc[bi + i0];
    float4 ciB = pc[bi + i1];
    int wA = __float_as_int(ciA.w);
    int wB = __float_as_int(ciB.w);
    int iresA = wA & 1023;
    int iresB = wB & 1023;
    int rowA, rowB;    // LDS path: (ti-tminI)*BINS element offset; global path: ti*BINS
    if (useLds) { rowA = ((wA >> 10) - tminI) * BINS; rowB = ((wB >> 10) - tminI) * BINS; }
    else        { rowA = (wA >> 10) * BINS;           rowB = (wB >> 10) * BINS; }
    __syncthreads();

    float a0 = 0.f, a1 = 0.f, a2 = 0.f, a3 = 0.f;
    float b0 = 0.f, b1 = 0.f, b2 = 0.f, b3 = 0.f;

#define PAIR_BODY(E_EXPR, CI, IRES, ROW, IEFF, ACC) do {               \
    float dx = CI.x - cj.x, dy = CI.y - cj.y, dz = CI.z - cj.z;        \
    float d2 = fmaf(dx, dx, fmaf(dy, dy, dz * dz));                    \
    int  sep = abs(IRES - jres);                                       \
    bool v = (sep > 2) & (d2 < 19.6f * 19.6f);                         \
    if (DIAG) v = v & (J > IEFF);                                      \
    float ds    = __builtin_amdgcn_sqrtf(d2) * (1.0f / 0.7f);          \
    float dsc   = fminf(ds, 27.0f);                                    \
    int   d0    = (int)dsc;                                            \
    float alpha = ds - (float)d0;                                      \
    float2 e = (E_EXPR);                                               \
    float en = fmaf(alpha, e.y - e.x, e.x);                            \
    ACC = fmaf(v ? 1.0f : 0.0f, en, ACC);                              \
} while (0)

    if (useLds) {
        int jj = tid >> 6;   // 0..3: wave-uniform j group (LDS broadcast preserved)
#define STEP2L(JX, AA, AB) do {                                        \
    const int J = (JX);                                                \
    float4 cj = jc[J];                                                 \
    int   wj   = __float_as_int(cj.w);                                 \
    int   jres = wj & 1023;                                            \
    int   jrow = wj >> 10;                                             \
    PAIR_BODY(sublut[jrow + rowA + d0], ciA, iresA, rowA, i0, AA);     \
    PAIR_BODY(sublut[jrow + rowB + d0], ciB, iresB, rowB, i1, AB);     \
} while (0)
        #pragma unroll
        for (int s = 0; s < 4; ++s, jj += 32) {
            STEP2L(jj,      a0, b0);
            STEP2L(jj + 4,  a1, b1);
            STEP2L(jj + 8,  a2, b2);
            STEP2L(jj + 12, a3, b3);
            STEP2L(jj + 16, a0, b0);
            STEP2L(jj + 20, a1, b1);
            STEP2L(jj + 24, a2, b2);
            STEP2L(jj + 28, a3, b3);
        }
#undef STEP2L
    } else {
        int jj = tid >> 6;
#define STEP2G(JX, AA, AB) do {                                        \
    const int J = (JX);                                                \
    float4 cj = jc[J];                                                 \
    int   wj   = __float_as_int(cj.w);                                 \
    int   jres = wj & 1023;                                            \
    int   tjb  = (wj >> 10) * NTB;                                     \
    PAIR_BODY(lut[tjb + rowA + d0], ciA, iresA, rowA, i0, AA);         \
    PAIR_BODY(lut[tjb + rowB + d0], ciB, iresB, rowB, i1, AB);         \
} while (0)
        #pragma unroll
        for (int s = 0; s < 4; ++s, jj += 32) {
            STEP2G(jj,      a0, b0);
            STEP2G(jj + 4,  a1, b1);
            STEP2G(jj + 8,  a2, b2);
            STEP2G(jj + 12, a3, b3);
            STEP2G(jj + 16, a0, b0);
            STEP2G(jj + 20, a1, b1);
            STEP2G(jj + 24, a2, b2);
            STEP2G(jj + 28, a3, b3);
        }
#undef STEP2G
    }
#undef PAIR_BODY

    float acc = ((a0 + a1) + (a2 + a3)) + ((b0 + b1) + (b2 + b3));
    for (int off = 32; off > 0; off >>= 1)
        acc += __shfl_down(acc, off, 64);
    if ((tid & 63) == 0) wsum[tid >> 6] = acc;
    __syncthreads();
    if (tid == 0) atomicAdd(out, (wsum[0] + wsum[1]) + (wsum[2] + wsum[3]));
}

// ---------------- fallback (ws too small): unsorted, direct pot reads, atomics ----------------
__global__ __launch_bounds__(256) void dfire_pairs_fb(
    const float* __restrict__ coords, const int* __restrict__ res,
    const int* __restrict__ type, const float* __restrict__ pot,
    float* __restrict__ out, int T) {

    __shared__ float jx[TILE], jy[TILE], jz[TILE];
    __shared__ int   jres[TILE], jtype[TILE];

    int k = blockIdx.x;
    int r = (int)((2.0 * T + 1.0 - sqrt((2.0 * T + 1.0) * (2.0 * T + 1.0) - 8.0 * (double)k)) * 0.5);
    if (r < 0) r = 0;
    if (r > T - 1) r = T - 1;
    while (r > 0 && (r * T - r * (r - 1) / 2) > k) --r;
    while (((r + 1) * T - (r + 1) * r / 2) <= k) ++r;
    int c = r + (k - (r * T - r * (r - 1) / 2));

    int bi = r * TILE, bj = c * TILE;
    int tid = threadIdx.x;
    if (tid < TILE) {
        int gj = bj + tid;
        jx[tid] = coords[3 * gj]; jy[tid] = coords[3 * gj + 1]; jz[tid] = coords[3 * gj + 2];
        jres[tid] = res[gj]; jtype[tid] = type[gj];
    }
    int ii = tid & (TILE - 1);
    int gi = bi + ii;
    float ix = coords[3 * gi], iy = coords[3 * gi + 1], iz = coords[3 * gi + 2];
    int ires = res[gi], it = type[gi];
    int ii_eff = (bi == bj) ? ii : -1;
    __syncthreads();

    float acc = 0.f;
    int jj = tid >> 7;
    for (int s = 0; s < TILE / 2; ++s, jj += 2) {
        float dx = ix - jx[jj], dy = iy - jy[jj], dz = iz - jz[jj];
        float d2 = dx * dx + dy * dy + dz * dz;
        float dist = sqrtf(d2) + 1e-8f;
        int sep = abs(ires - jres[jj]);
        bool v = (sep > 2) & (dist < 19.6f) & (jj > ii_eff);
        if (v) {
            float ds = dist * (1.0f / 0.7f);
            int d0 = (int)fminf(ds, 27.0f);
            int d1 = (d0 + 1 < BINS) ? d0 + 1 : BINS - 1;
            float alpha = ds - (float)d0;
            int row = (jtype[jj] * NT + it) * BINS;
            float e0 = pot[row + d0], e1 = pot[row + d1];
            acc += e0 + alpha * (e1 - e0);
        }
    }
    for (int off = 32; off > 0; off >>= 1)
        acc += __shfl_down(acc, off, 64);
    if ((tid & 63) == 0) atomicAdd(out, acc);
}

extern "C" void kernel_launch(void* const* d_in, const int* in_sizes, int n_in,
                              void* d_out, int out_size, void* d_ws, size_t ws_size,
                              hipStream_t stream) {
    const float* coords = (const float*)d_in[0];
    const float* pot    = (const float*)d_in[1];
    const int*   res    = (const int*)d_in[2];
    const int*   type   = (const int*)d_in[3];
    // d_in[4], d_in[5] (i_idx/j_idx) unused: pairs generated on the fly from triu structure.

    const int N = in_sizes[2];
    const int T = N / TILE;
    const int nblk = T * (T + 1) / 2;

    float* out = (float*)d_out;

    const size_t lutBytes  = (size_t)NT * NT * BINS * sizeof(float2);   // 1,618,400 (16B-aligned)
    const size_t pcBytes   = (size_t)N * sizeof(float4);
    const size_t offsBytes = 128 * sizeof(int);
    const size_t need = lutBytes + pcBytes + offsBytes;

    if (ws_size >= need) {
        char* w = (char*)d_ws;
        float2* lut  = (float2*)w;   w += lutBytes;
        float4* pc   = (float4*)w;   w += pcBytes;
        int*    offs = (int*)w;

        const int nOff = T * (T - 1) / 2;   // off-diagonal tiles
        // 4 launches: prep (repack ∥ hist/scan ∥ out=0) -> scatter -> pairs(off) -> pairs(diag)
        prep_k<<<RB + 1, 256, 0, stream>>>(pot, lut, type, offs, out, N);
        scatter_k<<<(N + 255) / 256, 256, 0, stream>>>(coords, res, type, offs, pc, N);
        dfire_pairs_t<false><<<nOff, 256, 0, stream>>>(pc, lut, out, T);
        dfire_pairs_t<true><<<T, 256, 0, stream>>>(pc, lut, out, T);
    } else {
        hipMemsetAsync(out, 0, sizeof(float), stream);
        dfire_pairs_fb<<<nblk, 256, 0, stream>>>(coords, res, type, pot, out, T);
    }
}

// Round 5
// 280.853 us; speedup vs baseline: 1.0063x; 1.0056x over previous
//
#include <hip/hip_runtime.h>

#define NT    85
#define BINS  28
#define NTB   (NT * BINS)      // 2380
#define TILE  128
#define MAXR  64               // max staged (tj,ti) LUT rows in LDS (64*32*8B = 16384 B)
#define RB    ((NT * NT * BINS + 255) / 256)   // 791 repack blocks

// readlane helper: wave-uniform broadcast of one lane's 32-bit value (SALU-resident result)
#define RDLNF(V, LN) __int_as_float(__builtin_amdgcn_readlane(__float_as_int(V), (LN)))
#define RDLNI(V, LN) __builtin_amdgcn_readlane(__float_as_int(V), (LN))

// ---------------- prep: repack LUT (blocks 0..RB-1)  +  hist/scan + out=0 (block RB) ----------------
__global__ __launch_bounds__(256) void prep_k(const float* __restrict__ pot,
                                              float2* __restrict__ lut,
                                              const int* __restrict__ type,
                                              int* __restrict__ offs,
                                              float* __restrict__ out, int N) {
    const int total = NT * NT * BINS;
    if (blockIdx.x < RB) {
        int idx = blockIdx.x * 256 + threadIdx.x;
        if (idx < total) {
            int d  = idx % BINS;
            int ab = idx / BINS;
            int d1 = (d + 1 < BINS) ? d + 1 : BINS - 1;
            lut[idx] = make_float2(pot[idx], pot[ab * BINS + d1]);
        }
    } else {
        __shared__ int h[NT];
        for (int t = threadIdx.x; t < NT; t += 256) h[t] = 0;
        __syncthreads();
        for (int i = threadIdx.x; i < N; i += 256) atomicAdd(&h[type[i]], 1);
        __syncthreads();
        if (threadIdx.x == 0) {
            int s = 0;
            for (int t = 0; t < NT; ++t) { int c = h[t]; offs[t] = s; s += c; }
            out[0] = 0.0f;
        }
    }
}

// pack atom: (x, y, z, bits(type<<10 | res)); res < 1024, type < 128
__global__ void scatter_k(const float* __restrict__ coords, const int* __restrict__ res,
                          const int* __restrict__ type, int* __restrict__ offs,
                          float4* __restrict__ pc, int N) {
    int i = blockIdx.x * blockDim.x + threadIdx.x;
    if (i >= N) return;
    int t = type[i];
    int p = atomicAdd(&offs[t], 1);
    pc[p] = make_float4(coords[3 * i], coords[3 * i + 1], coords[3 * i + 2],
                        __int_as_float((t << 10) | res[i]));
}

// ---------------- main pair kernel ----------------
// j-tile lives in REGISTERS (cjLo/cjHi, identical in all waves); per-step j atom is fetched
// with v_readlane (wave-uniform lane index) -> zero LDS traffic for j, decode on SALU.
// LDS holds only the block's sub-LUT (rows padded to stride 32 for shift indexing).
// DIAG=false: strict upper-triangle off-diagonal tiles. DIAG=true: diagonal tiles.
template <bool DIAG>
__global__ __launch_bounds__(256) void dfire_pairs_t(
    const float4* __restrict__ pc,
    const float2* __restrict__ lut,
    float* __restrict__ out, int T) {

    __shared__ float2 sublut[MAXR * 32];
    __shared__ float  wsum[4];

    int r, c;
    if (DIAG) {
        r = blockIdx.x; c = r;
    } else {
        // strict upper triangle: row r has (T-1-r) entries; prefix P(r) = r*(T-1) - r*(r-1)/2
        int k = blockIdx.x;
        double tm = 2.0 * T - 1.0;
        double disc = tm * tm - 8.0 * (double)k;
        if (disc < 0.0) disc = 0.0;
        r = (int)((tm - sqrt(disc)) * 0.5);
        if (r < 0) r = 0;
        if (r > T - 2) r = T - 2;
        while (r > 0 && (r * (T - 1) - r * (r - 1) / 2) > k) --r;
        while (((r + 1) * (T - 1) - (r + 1) * r / 2) <= k) ++r;
        c = r + 1 + (k - (r * (T - 1) - r * (r - 1) / 2));
    }

    int bi = r * TILE, bj = c * TILE;
    int tid  = threadIdx.x;
    int lane = tid & 63;

    // contiguous type windows of the two tiles (atoms sorted by type)
    int tminI = __float_as_int(pc[bi].w) >> 10;
    int tmaxI = __float_as_int(pc[bi + TILE - 1].w) >> 10;
    int tminJ = __float_as_int(pc[bj].w) >> 10;
    int tmaxJ = __float_as_int(pc[bj + TILE - 1].w) >> 10;
    int nI = tmaxI - tminI + 1;
    int nRows = nI * (tmaxJ - tminJ + 1);
    bool useLds = (nRows <= MAXR);          // block-uniform
    int nI32 = nI << 5;

    // j atoms in registers — identical content in every wave
    float4 cjLo = pc[bj + lane];
    float4 cjHi = pc[bj + 64 + lane];

    if (useLds) {
        int tot = nRows << 5;
        for (int x = tid; x < tot; x += 256) {
            int u = x >> 5, d = x & 31;
            int cjl = u / nI, cil = u - cjl * nI;
            sublut[x] = (d < BINS)
                ? lut[(tminJ + cjl) * NTB + (tminI + cil) * BINS + d]
                : make_float2(0.f, 0.f);
        }
    }

    // each thread owns TWO i atoms (lane, lane+64) and 32 j's at stride 4
    int i0 = lane;
    int i1 = lane + 64;
    float4 ciA = pc[bi + i0];
    float4 ciB = pc[bi + i1];
    int wA = __float_as_int(ciA.w);
    int wB = __float_as_int(ciB.w);
    int iresA = wA & 1023;
    int iresB = wB & 1023;
    int rowA, rowB;    // LDS path: (ti-tminI)*32 element offset; global path: ti*BINS
    if (useLds) { rowA = ((wA >> 10) - tminI) << 5; rowB = ((wB >> 10) - tminI) << 5; }
    else        { rowA = (wA >> 10) * BINS;         rowB = (wB >> 10) * BINS; }
    __syncthreads();

    float a0 = 0.f, a1 = 0.f, a2 = 0.f, a3 = 0.f;
    float b0 = 0.f, b1 = 0.f, b2 = 0.f, b3 = 0.f;
    int jj0 = tid >> 6;   // wave id 0..3 — wave-uniform

#define PAIR_LDS(CI, IRES, ROW, IEFF, ACC) do {                        \
    float dx = CI.x - jx, dy = CI.y - jy, dz = CI.z - jz;              \
    float d2 = fmaf(dx, dx, fmaf(dy, dy, dz * dz));                    \
    int  sep = abs(IRES - jres);                                       \
    bool v = (sep > 2) & (d2 < 19.6f * 19.6f);                         \
    if (DIAG) v = v & (J > IEFF);                                      \
    float ds    = __builtin_amdgcn_sqrtf(d2) * (1.0f / 0.7f);          \
    float dsc   = fminf(ds, 31.0f);                                    \
    int   d0    = (int)dsc;                                            \
    float alpha = ds - (float)d0;                                      \
    float2 e = sublut[jrow + ROW + d0];                                \
    float en = fmaf(alpha, e.y - e.x, e.x);                            \
    ACC = fmaf(v ? 1.0f : 0.0f, en, ACC);                              \
} while (0)

#define PAIR_GBL(CI, IRES, ROW, IEFF, ACC) do {                        \
    float dx = CI.x - jx, dy = CI.y - jy, dz = CI.z - jz;              \
    float d2 = fmaf(dx, dx, fmaf(dy, dy, dz * dz));                    \
    int  sep = abs(IRES - jres);                                       \
    bool v = (sep > 2) & (d2 < 19.6f * 19.6f);                         \
    if (DIAG) v = v & (J > IEFF);                                      \
    float ds    = __builtin_amdgcn_sqrtf(d2) * (1.0f / 0.7f);          \
    float dsc   = fminf(ds, 27.0f);                                    \
    int   d0    = (int)dsc;                                            \
    float alpha = ds - (float)d0;                                      \
    float2 e = lut[tjb + ROW + d0];                                    \
    float en = fmaf(alpha, e.y - e.x, e.x);                            \
    ACC = fmaf(v ? 1.0f : 0.0f, en, ACC);                              \
} while (0)

    if (useLds) {
#define STEP2L(OFF, SRC, LN, AA, AB) do {                              \
    const int J  = jj0 + (OFF);                                        \
    const int ln = (LN);                                               \
    float jx = RDLNF(SRC.x, ln), jy = RDLNF(SRC.y, ln),                \
          jz = RDLNF(SRC.z, ln);                                       \
    int   wj = RDLNI(SRC.w, ln);                                       \
    int jres = wj & 1023;                                              \
    int jrow = ((wj >> 10) - tminJ) * nI32;                            \
    PAIR_LDS(ciA, iresA, rowA, i0, AA);                                \
    PAIR_LDS(ciB, iresB, rowB, i1, AB);                                \
} while (0)
        #pragma unroll
        for (int s = 0; s < 2; ++s) {          // OFF 0..60: j < 64 -> cjLo
            int base = 32 * s;
            STEP2L(base + 0,  cjLo, jj0 + base + 0,  a0, b0);
            STEP2L(base + 4,  cjLo, jj0 + base + 4,  a1, b1);
            STEP2L(base + 8,  cjLo, jj0 + base + 8,  a2, b2);
            STEP2L(base + 12, cjLo, jj0 + base + 12, a3, b3);
            STEP2L(base + 16, cjLo, jj0 + base + 16, a0, b0);
            STEP2L(base + 20, cjLo, jj0 + base + 20, a1, b1);
            STEP2L(base + 24, cjLo, jj0 + base + 24, a2, b2);
            STEP2L(base + 28, cjLo, jj0 + base + 28, a3, b3);
        }
        #pragma unroll
        for (int s = 2; s < 4; ++s) {          // OFF 64..124: j >= 64 -> cjHi
            int base = 32 * s;
            STEP2L(base + 0,  cjHi, jj0 + base + 0  - 64, a0, b0);
            STEP2L(base + 4,  cjHi, jj0 + base + 4  - 64, a1, b1);
            STEP2L(base + 8,  cjHi, jj0 + base + 8  - 64, a2, b2);
            STEP2L(base + 12, cjHi, jj0 + base + 12 - 64, a3, b3);
            STEP2L(base + 16, cjHi, jj0 + base + 16 - 64, a0, b0);
            STEP2L(base + 20, cjHi, jj0 + base + 20 - 64, a1, b1);
            STEP2L(base + 24, cjHi, jj0 + base + 24 - 64, a2, b2);
            STEP2L(base + 28, cjHi, jj0 + base + 28 - 64, a3, b3);
        }
#undef STEP2L
    } else {
#define STEP2G(OFF, SRC, LN, AA, AB) do {                              \
    const int J  = jj0 + (OFF);                                        \
    const int ln = (LN);                                               \
    float jx = RDLNF(SRC.x, ln), jy = RDLNF(SRC.y, ln),                \
          jz = RDLNF(SRC.z, ln);                                       \
    int   wj = RDLNI(SRC.w, ln);                                       \
    int jres = wj & 1023;                                              \
    int tjb  = (wj >> 10) * NTB;                                       \
    PAIR_GBL(ciA, iresA, rowA, i0, AA);                                \
    PAIR_GBL(ciB, iresB, rowB, i1, AB);                                \
} while (0)
        #pragma unroll
        for (int s = 0; s < 2; ++s) {
            int base = 32 * s;
            STEP2G(base + 0,  cjLo, jj0 + base + 0,  a0, b0);
            STEP2G(base + 4,  cjLo, jj0 + base + 4,  a1, b1);
            STEP2G(base + 8,  cjLo, jj0 + base + 8,  a2, b2);
            STEP2G(base + 12, cjLo, jj0 + base + 12, a3, b3);
            STEP2G(base + 16, cjLo, jj0 + base + 16, a0, b0);
            STEP2G(base + 20, cjLo, jj0 + base + 20, a1, b1);
            STEP2G(base + 24, cjLo, jj0 + base + 24, a2, b2);
            STEP2G(base + 28, cjLo, jj0 + base + 28, a3, b3);
        }
        #pragma unroll
        for (int s = 2; s < 4; ++s) {
            int base = 32 * s;
            STEP2G(base + 0,  cjHi, jj0 + base + 0  - 64, a0, b0);
            STEP2G(base + 4,  cjHi, jj0 + base + 4  - 64, a1, b1);
            STEP2G(base + 8,  cjHi, jj0 + base + 8  - 64, a2, b2);
            STEP2G(base + 12, cjHi, jj0 + base + 12 - 64, a3, b3);
            STEP2G(base + 16, cjHi, jj0 + base + 16 - 64, a0, b0);
            STEP2G(base + 20, cjHi, jj0 + base + 20 - 64, a1, b1);
            STEP2G(base + 24, cjHi, jj0 + base + 24 - 64, a2, b2);
            STEP2G(base + 28, cjHi, jj0 + base + 28 - 64, a3, b3);
        }
#undef STEP2G
    }
#undef PAIR_LDS
#undef PAIR_GBL

    float acc = ((a0 + a1) + (a2 + a3)) + ((b0 + b1) + (b2 + b3));
    for (int off = 32; off > 0; off >>= 1)
        acc += __shfl_down(acc, off, 64);
    if ((tid & 63) == 0) wsum[tid >> 6] = acc;
    __syncthreads();
    if (tid == 0) atomicAdd(out, (wsum[0] + wsum[1]) + (wsum[2] + wsum[3]));
}

// ---------------- fallback (ws too small): unsorted, direct pot reads, atomics ----------------
__global__ __launch_bounds__(256) void dfire_pairs_fb(
    const float* __restrict__ coords, const int* __restrict__ res,
    const int* __restrict__ type, const float* __restrict__ pot,
    float* __restrict__ out, int T) {

    __shared__ float jx[TILE], jy[TILE], jz[TILE];
    __shared__ int   jres[TILE], jtype[TILE];

    int k = blockIdx.x;
    int r = (int)((2.0 * T + 1.0 - sqrt((2.0 * T + 1.0) * (2.0 * T + 1.0) - 8.0 * (double)k)) * 0.5);
    if (r < 0) r = 0;
    if (r > T - 1) r = T - 1;
    while (r > 0 && (r * T - r * (r - 1) / 2) > k) --r;
    while (((r + 1) * T - (r + 1) * r / 2) <= k) ++r;
    int c = r + (k - (r * T - r * (r - 1) / 2));

    int bi = r * TILE, bj = c * TILE;
    int tid = threadIdx.x;
    if (tid < TILE) {
        int gj = bj + tid;
        jx[tid] = coords[3 * gj]; jy[tid] = coords[3 * gj + 1]; jz[tid] = coords[3 * gj + 2];
        jres[tid] = res[gj]; jtype[tid] = type[gj];
    }
    int ii = tid & (TILE - 1);
    int gi = bi + ii;
    float ix = coords[3 * gi], iy = coords[3 * gi + 1], iz = coords[3 * gi + 2];
    int ires = res[gi], it = type[gi];
    int ii_eff = (bi == bj) ? ii : -1;
    __syncthreads();

    float acc = 0.f;
    int jj = tid >> 7;
    for (int s = 0; s < TILE / 2; ++s, jj += 2) {
        float dx = ix - jx[jj], dy = iy - jy[jj], dz = iz - jz[jj];
        float d2 = dx * dx + dy * dy + dz * dz;
        float dist = sqrtf(d2) + 1e-8f;
        int sep = abs(ires - jres[jj]);
        bool v = (sep > 2) & (dist < 19.6f) & (jj > ii_eff);
        if (v) {
            float ds = dist * (1.0f / 0.7f);
            int d0 = (int)fminf(ds, 27.0f);
            int d1 = (d0 + 1 < BINS) ? d0 + 1 : BINS - 1;
            float alpha = ds - (float)d0;
            int row = (jtype[jj] * NT + it) * BINS;
            float e0 = pot[row + d0], e1 = pot[row + d1];
            acc += e0 + alpha * (e1 - e0);
        }
    }
    for (int off = 32; off > 0; off >>= 1)
        acc += __shfl_down(acc, off, 64);
    if ((tid & 63) == 0) atomicAdd(out, acc);
}

extern "C" void kernel_launch(void* const* d_in, const int* in_sizes, int n_in,
                              void* d_out, int out_size, void* d_ws, size_t ws_size,
                              hipStream_t stream) {
    const float* coords = (const float*)d_in[0];
    const float* pot    = (const float*)d_in[1];
    const int*   res    = (const int*)d_in[2];
    const int*   type   = (const int*)d_in[3];
    // d_in[4], d_in[5] (i_idx/j_idx) unused: pairs generated on the fly from triu structure.

    const int N = in_sizes[2];
    const int T = N / TILE;
    const int nblk = T * (T + 1) / 2;

    float* out = (float*)d_out;

    const size_t lutBytes  = (size_t)NT * NT * BINS * sizeof(float2);   // 1,618,400 (16B-aligned)
    const size_t pcBytes   = (size_t)N * sizeof(float4);
    const size_t offsBytes = 128 * sizeof(int);
    const size_t need = lutBytes + pcBytes + offsBytes;

    if (ws_size >= need) {
        char* w = (char*)d_ws;
        float2* lut  = (float2*)w;   w += lutBytes;
        float4* pc   = (float4*)w;   w += pcBytes;
        int*    offs = (int*)w;

        const int nOff = T * (T - 1) / 2;   // off-diagonal tiles
        // 4 launches: prep (repack ∥ hist/scan ∥ out=0) -> scatter -> pairs(off) -> pairs(diag)
        prep_k<<<RB + 1, 256, 0, stream>>>(pot, lut, type, offs, out, N);
        scatter_k<<<(N + 255) / 256, 256, 0, stream>>>(coords, res, type, offs, pc, N);
        dfire_pairs_t<false><<<nOff, 256, 0, stream>>>(pc, lut, out, T);
        dfire_pairs_t<true><<<T, 256, 0, stream>>>(pc, lut, out, T);
    } else {
        hipMemsetAsync(out, 0, sizeof(float), stream);
        dfire_pairs_fb<<<nblk, 256, 0, stream>>>(coords, res, type, pot, out, T);
    }
}

// Round 7
// 276.395 us; speedup vs baseline: 1.0226x; 1.0161x over previous
//
#include <hip/hip_runtime.h>

#define NT    85
#define BINS  28
#define NTB   (NT * BINS)      // 2380
#define TILE  128
#define MAXR  64               // max staged (tj,ti) LUT rows in LDS (64*32*8B = 16384 B)
#define RB    ((NT * NT * BINS + 255) / 256)   // 791 repack blocks

// readlane helper: wave-uniform broadcast of one lane's 32-bit value (SALU-resident result)
#define RDLNF(V, LN) __int_as_float(__builtin_amdgcn_readlane(__float_as_int(V), (LN)))
#define RDLNI(V, LN) __builtin_amdgcn_readlane(__float_as_int(V), (LN))

// ---------------- prep: repack LUT (blocks 0..RB-1)  +  hist/scan + out=0 (block RB) ----------------
__global__ __launch_bounds__(256) void prep_k(const float* __restrict__ pot,
                                              float2* __restrict__ lut,
                                              const int* __restrict__ type,
                                              int* __restrict__ offs,
                                              float* __restrict__ out, int N) {
    const int total = NT * NT * BINS;
    if (blockIdx.x < RB) {
        int idx = blockIdx.x * 256 + threadIdx.x;
        if (idx < total) {
            int d  = idx % BINS;
            int ab = idx / BINS;
            int d1 = (d + 1 < BINS) ? d + 1 : BINS - 1;
            lut[idx] = make_float2(pot[idx], pot[ab * BINS + d1]);
        }
    } else {
        __shared__ int h[NT];
        for (int t = threadIdx.x; t < NT; t += 256) h[t] = 0;
        __syncthreads();
        for (int i = threadIdx.x; i < N; i += 256) atomicAdd(&h[type[i]], 1);
        __syncthreads();
        if (threadIdx.x == 0) {
            int s = 0;
            for (int t = 0; t < NT; ++t) { int c = h[t]; offs[t] = s; s += c; }
            out[0] = 0.0f;
        }
    }
}

// pack atom: (x, y, z, bits(type<<10 | res)); res < 1024, type < 128
__global__ void scatter_k(const float* __restrict__ coords, const int* __restrict__ res,
                          const int* __restrict__ type, int* __restrict__ offs,
                          float4* __restrict__ pc, int N) {
    int i = blockIdx.x * blockDim.x + threadIdx.x;
    if (i >= N) return;
    int t = type[i];
    int p = atomicAdd(&offs[t], 1);
    pc[p] = make_float4(coords[3 * i], coords[3 * i + 1], coords[3 * i + 2],
                        __int_as_float((t << 10) | res[i]));
}

// ---------------- tile body ----------------
// j-tile in REGISTERS (cjLo/cjHi, identical in all waves); per-step j atom fetched with
// v_readlane (wave-uniform lane index) -> zero LDS traffic for j, decode on SALU.
// LDS holds only the block's sub-LUT (rows padded to stride 32 for shift indexing).
// DIAG=false: strict upper-triangle off-diagonal tile. DIAG=true: diagonal tile.
template <bool DIAG>
__device__ __forceinline__ void tile_body(int k,
                                          const float4* __restrict__ pc,
                                          const float2* __restrict__ lut,
                                          float* __restrict__ out, int T,
                                          float2* sublut, float* wsum) {
    int r, c;
    if (DIAG) {
        r = k; c = k;
    } else {
        // strict upper triangle: row r has (T-1-r) entries; prefix P(r) = r*(T-1) - r*(r-1)/2
        double tm = 2.0 * T - 1.0;
        double disc = tm * tm - 8.0 * (double)k;
        if (disc < 0.0) disc = 0.0;
        r = (int)((tm - sqrt(disc)) * 0.5);
        if (r < 0) r = 0;
        if (r > T - 2) r = T - 2;
        while (r > 0 && (r * (T - 1) - r * (r - 1) / 2) > k) --r;
        while (((r + 1) * (T - 1) - (r + 1) * r / 2) <= k) ++r;
        c = r + 1 + (k - (r * (T - 1) - r * (r - 1) / 2));
    }

    int bi = r * TILE, bj = c * TILE;
    int tid  = threadIdx.x;
    int lane = tid & 63;

    // contiguous type windows of the two tiles (atoms sorted by type)
    int tminI = __float_as_int(pc[bi].w) >> 10;
    int tmaxI = __float_as_int(pc[bi + TILE - 1].w) >> 10;
    int tminJ = __float_as_int(pc[bj].w) >> 10;
    int tmaxJ = __float_as_int(pc[bj + TILE - 1].w) >> 10;
    int nI = tmaxI - tminI + 1;
    int nRows = nI * (tmaxJ - tminJ + 1);
    bool useLds = (nRows <= MAXR);          // block-uniform
    int nI32 = nI << 5;

    // j atoms in registers — identical content in every wave
    float4 cjLo = pc[bj + lane];
    float4 cjHi = pc[bj + 64 + lane];

    if (useLds) {
        int tot = nRows << 5;
        for (int x = tid; x < tot; x += 256) {
            int u = x >> 5, d = x & 31;
            int cjl = u / nI, cil = u - cjl * nI;
            sublut[x] = (d < BINS)
                ? lut[(tminJ + cjl) * NTB + (tminI + cil) * BINS + d]
                : make_float2(0.f, 0.f);
        }
    }

    // each thread owns TWO i atoms (lane, lane+64) and 32 j's at stride 4
    int i0 = lane;
    int i1 = lane + 64;
    float4 ciA = pc[bi + i0];
    float4 ciB = pc[bi + i1];
    int wA = __float_as_int(ciA.w);
    int wB = __float_as_int(ciB.w);
    int iresA = wA & 1023;
    int iresB = wB & 1023;
    int rowA, rowB;    // LDS path: (ti-tminI)*32 element offset; global path: ti*BINS
    if (useLds) { rowA = ((wA >> 10) - tminI) << 5; rowB = ((wB >> 10) - tminI) << 5; }
    else        { rowA = (wA >> 10) * BINS;         rowB = (wB >> 10) * BINS; }
    __syncthreads();

    float a0 = 0.f, a1 = 0.f, a2 = 0.f, a3 = 0.f;
    float b0 = 0.f, b1 = 0.f, b2 = 0.f, b3 = 0.f;
    int jj0 = tid >> 6;   // wave id 0..3 — wave-uniform

#define PAIR_LDS(CI, IRES, ROW, IEFF, ACC) do {                        \
    float dx = CI.x - jx, dy = CI.y - jy, dz = CI.z - jz;              \
    float d2 = fmaf(dx, dx, fmaf(dy, dy, dz * dz));                    \
    int  sep = abs(IRES - jres);                                       \
    bool v = (sep > 2) & (d2 < 19.6f * 19.6f);                         \
    if (DIAG) v = v & (J > IEFF);                                      \
    float ds    = __builtin_amdgcn_sqrtf(d2) * (1.0f / 0.7f);          \
    float dsc   = fminf(ds, 31.0f);                                    \
    int   d0    = (int)dsc;                                            \
    float alpha = ds - (float)d0;                                      \
    float2 e = sublut[jrow + ROW + d0];                                \
    float en = fmaf(alpha, e.y - e.x, e.x);                            \
    ACC = fmaf(v ? 1.0f : 0.0f, en, ACC);                              \
} while (0)

#define PAIR_GBL(CI, IRES, ROW, IEFF, ACC) do {                        \
    float dx = CI.x - jx, dy = CI.y - jy, dz = CI.z - jz;              \
    float d2 = fmaf(dx, dx, fmaf(dy, dy, dz * dz));                    \
    int  sep = abs(IRES - jres);                                       \
    bool v = (sep > 2) & (d2 < 19.6f * 19.6f);                         \
    if (DIAG) v = v & (J > IEFF);                                      \
    float ds    = __builtin_amdgcn_sqrtf(d2) * (1.0f / 0.7f);          \
    float dsc   = fminf(ds, 27.0f);                                    \
    int   d0    = (int)dsc;                                            \
    float alpha = ds - (float)d0;                                      \
    float2 e = lut[tjb + ROW + d0];                                    \
    float en = fmaf(alpha, e.y - e.x, e.x);                            \
    ACC = fmaf(v ? 1.0f : 0.0f, en, ACC);                              \
} while (0)

    if (useLds) {
#define STEP2L(OFF, SRC, LN, AA, AB) do {                              \
    const int J  = jj0 + (OFF);                                        \
    const int ln = (LN);                                               \
    float jx = RDLNF(SRC.x, ln), jy = RDLNF(SRC.y, ln),                \
          jz = RDLNF(SRC.z, ln);                                       \
    int   wj = RDLNI(SRC.w, ln);                                       \
    int jres = wj & 1023;                                              \
    int jrow = ((wj >> 10) - tminJ) * nI32;                            \
    PAIR_LDS(ciA, iresA, rowA, i0, AA);                                \
    PAIR_LDS(ciB, iresB, rowB, i1, AB);                                \
} while (0)
        #pragma unroll
        for (int s = 0; s < 2; ++s) {          // OFF 0..60: j < 64 -> cjLo
            int base = 32 * s;
            STEP2L(base + 0,  cjLo, jj0 + base + 0,  a0, b0);
            STEP2L(base + 4,  cjLo, jj0 + base + 4,  a1, b1);
            STEP2L(base + 8,  cjLo, jj0 + base + 8,  a2, b2);
            STEP2L(base + 12, cjLo, jj0 + base + 12, a3, b3);
            STEP2L(base + 16, cjLo, jj0 + base + 16, a0, b0);
            STEP2L(base + 20, cjLo, jj0 + base + 20, a1, b1);
            STEP2L(base + 24, cjLo, jj0 + base + 24, a2, b2);
            STEP2L(base + 28, cjLo, jj0 + base + 28, a3, b3);
        }
        #pragma unroll
        for (int s = 2; s < 4; ++s) {          // OFF 64..124: j >= 64 -> cjHi
            int base = 32 * s;
            STEP2L(base + 0,  cjHi, jj0 + base + 0  - 64, a0, b0);
            STEP2L(base + 4,  cjHi, jj0 + base + 4  - 64, a1, b1);
            STEP2L(base + 8,  cjHi, jj0 + base + 8  - 64, a2, b2);
            STEP2L(base + 12, cjHi, jj0 + base + 12 - 64, a3, b3);
            STEP2L(base + 16, cjHi, jj0 + base + 16 - 64, a0, b0);
            STEP2L(base + 20, cjHi, jj0 + base + 20 - 64, a1, b1);
            STEP2L(base + 24, cjHi, jj0 + base + 24 - 64, a2, b2);
            STEP2L(base + 28, cjHi, jj0 + base + 28 - 64, a3, b3);
        }
#undef STEP2L
    } else {
#define STEP2G(OFF, SRC, LN, AA, AB) do {                              \
    const int J  = jj0 + (OFF);                                        \
    const int ln = (LN);                                               \
    float jx = RDLNF(SRC.x, ln), jy = RDLNF(SRC.y, ln),                \
          jz = RDLNF(SRC.z, ln);                                       \
    int   wj = RDLNI(SRC.w, ln);                                       \
    int jres = wj & 1023;                                              \
    int tjb  = (wj >> 10) * NTB;                                       \
    PAIR_GBL(ciA, iresA, rowA, i0, AA);                                \
    PAIR_GBL(ciB, iresB, rowB, i1, AB);                                \
} while (0)
        #pragma unroll
        for (int s = 0; s < 2; ++s) {
            int base = 32 * s;
            STEP2G(base + 0,  cjLo, jj0 + base + 0,  a0, b0);
            STEP2G(base + 4,  cjLo, jj0 + base + 4,  a1, b1);
            STEP2G(base + 8,  cjLo, jj0 + base + 8,  a2, b2);
            STEP2G(base + 12, cjLo, jj0 + base + 12, a3, b3);
            STEP2G(base + 16, cjLo, jj0 + base + 16, a0, b0);
            STEP2G(base + 20, cjLo, jj0 + base + 20, a1, b1);
            STEP2G(base + 24, cjLo, jj0 + base + 24, a2, b2);
            STEP2G(base + 28, cjLo, jj0 + base + 28, a3, b3);
        }
        #pragma unroll
        for (int s = 2; s < 4; ++s) {
            int base = 32 * s;
            STEP2G(base + 0,  cjHi, jj0 + base + 0  - 64, a0, b0);
            STEP2G(base + 4,  cjHi, jj0 + base + 4  - 64, a1, b1);
            STEP2G(base + 8,  cjHi, jj0 + base + 8  - 64, a2, b2);
            STEP2G(base + 12, cjHi, jj0 + base + 12 - 64, a3, b3);
            STEP2G(base + 16, cjHi, jj0 + base + 16 - 64, a0, b0);
            STEP2G(base + 20, cjHi, jj0 + base + 20 - 64, a1, b1);
            STEP2G(base + 24, cjHi, jj0 + base + 24 - 64, a2, b2);
            STEP2G(base + 28, cjHi, jj0 + base + 28 - 64, a3, b3);
        }
#undef STEP2G
    }
#undef PAIR_LDS
#undef PAIR_GBL

    float acc = ((a0 + a1) + (a2 + a3)) + ((b0 + b1) + (b2 + b3));
    for (int off = 32; off > 0; off >>= 1)
        acc += __shfl_down(acc, off, 64);
    if ((tid & 63) == 0) wsum[tid >> 6] = acc;
    __syncthreads();
    if (tid == 0) atomicAdd(out, (wsum[0] + wsum[1]) + (wsum[2] + wsum[3]));
}

// ---------------- unified pair kernel: blocks [0,nOff) = off-diag, [nOff,nOff+T) = diag ----------------
__global__ __launch_bounds__(256) void dfire_pairs_all(
    const float4* __restrict__ pc,
    const float2* __restrict__ lut,
    float* __restrict__ out, int T, int nOff) {

    __shared__ float2 sublut[MAXR * 32];
    __shared__ float  wsum[4];

    int k = blockIdx.x;
    if (k < nOff) tile_body<false>(k, pc, lut, out, T, sublut, wsum);
    else          tile_body<true >(k - nOff, pc, lut, out, T, sublut, wsum);
}

// ---------------- fallback (ws too small): unsorted, direct pot reads, atomics ----------------
__global__ __launch_bounds__(256) void dfire_pairs_fb(
    const float* __restrict__ coords, const int* __restrict__ res,
    const int* __restrict__ type, const float* __restrict__ pot,
    float* __restrict__ out, int T) {

    __shared__ float jx[TILE], jy[TILE], jz[TILE];
    __shared__ int   jres[TILE], jtype[TILE];

    int k = blockIdx.x;
    int r = (int)((2.0 * T + 1.0 - sqrt((2.0 * T + 1.0) * (2.0 * T + 1.0) - 8.0 * (double)k)) * 0.5);
    if (r < 0) r = 0;
    if (r > T - 1) r = T - 1;
    while (r > 0 && (r * T - r * (r - 1) / 2) > k) --r;
    while (((r + 1) * T - (r + 1) * r / 2) <= k) ++r;
    int c = r + (k - (r * T - r * (r - 1) / 2));

    int bi = r * TILE, bj = c * TILE;
    int tid = threadIdx.x;
    if (tid < TILE) {
        int gj = bj + tid;
        jx[tid] = coords[3 * gj]; jy[tid] = coords[3 * gj + 1]; jz[tid] = coords[3 * gj + 2];
        jres[tid] = res[gj]; jtype[tid] = type[gj];
    }
    int ii = tid & (TILE - 1);
    int gi = bi + ii;
    float ix = coords[3 * gi], iy = coords[3 * gi + 1], iz = coords[3 * gi + 2];
    int ires = res[gi], it = type[gi];
    int ii_eff = (bi == bj) ? ii : -1;
    __syncthreads();

    float acc = 0.f;
    int jj = tid >> 7;
    for (int s = 0; s < TILE / 2; ++s, jj += 2) {
        float dx = ix - jx[jj], dy = iy - jy[jj], dz = iz - jz[jj];
        float d2 = dx * dx + dy * dy + dz * dz;
        float dist = sqrtf(d2) + 1e-8f;
        int sep = abs(ires - jres[jj]);
        bool v = (sep > 2) & (dist < 19.6f) & (jj > ii_eff);
        if (v) {
            float ds = dist * (1.0f / 0.7f);
            int d0 = (int)fminf(ds, 27.0f);
            int d1 = (d0 + 1 < BINS) ? d0 + 1 : BINS - 1;
            float alpha = ds - (float)d0;
            int row = (jtype[jj] * NT + it) * BINS;
            float e0 = pot[row + d0], e1 = pot[row + d1];
            acc += e0 + alpha * (e1 - e0);
        }
    }
    for (int off = 32; off > 0; off >>= 1)
        acc += __shfl_down(acc, off, 64);
    if ((tid & 63) == 0) atomicAdd(out, acc);
}

extern "C" void kernel_launch(void* const* d_in, const int* in_sizes, int n_in,
                              void* d_out, int out_size, void* d_ws, size_t ws_size,
                              hipStream_t stream) {
    const float* coords = (const float*)d_in[0];
    const float* pot    = (const float*)d_in[1];
    const int*   res    = (const int*)d_in[2];
    const int*   type   = (const int*)d_in[3];
    // d_in[4], d_in[5] (i_idx/j_idx) unused: pairs generated on the fly from triu structure.

    const int N = in_sizes[2];
    const int T = N / TILE;
    const int nblk = T * (T + 1) / 2;

    float* out = (float*)d_out;

    const size_t lutBytes  = (size_t)NT * NT * BINS * sizeof(float2);   // 1,618,400 (16B-aligned)
    const size_t pcBytes   = (size_t)N * sizeof(float4);
    const size_t offsBytes = 128 * sizeof(int);
    const size_t need = lutBytes + pcBytes + offsBytes;

    if (ws_size >= need) {
        char* w = (char*)d_ws;
        float2* lut  = (float2*)w;   w += lutBytes;
        float4* pc   = (float4*)w;   w += pcBytes;
        int*    offs = (int*)w;

        const int nOff = T * (T - 1) / 2;   // off-diagonal tiles
        // 3 launches: prep (repack ∥ hist/scan ∥ out=0) -> scatter -> pairs(off+diag merged)
        prep_k<<<RB + 1, 256, 0, stream>>>(pot, lut, type, offs, out, N);
        scatter_k<<<(N + 255) / 256, 256, 0, stream>>>(coords, res, type, offs, pc, N);
        dfire_pairs_all<<<nOff + T, 256, 0, stream>>>(pc, lut, out, T, nOff);
    } else {
        hipMemsetAsync(out, 0, sizeof(float), stream);
        dfire_pairs_fb<<<nblk, 256, 0, stream>>>(coords, res, type, pot, out, T);
    }
}

// Round 8
// 274.896 us; speedup vs baseline: 1.0281x; 1.0055x over previous
//
#include <hip/hip_runtime.h>

#define NT    85
#define BINS  28
#define NTB   (NT * BINS)      // 2380
#define TILE  128
#define MAXR  64               // max staged (tj,ti) LUT rows in LDS (64*32*8B = 16384 B)

// ---------------- hist/scan (one block) + out=0 ----------------
__global__ __launch_bounds__(256) void hist_k(const int* __restrict__ type,
                                              int* __restrict__ offs,
                                              float* __restrict__ out, int N) {
    __shared__ int h[NT];
    for (int t = threadIdx.x; t < NT; t += 256) h[t] = 0;
    __syncthreads();
    for (int i = threadIdx.x; i < N; i += 256) atomicAdd(&h[type[i]], 1);
    __syncthreads();
    if (threadIdx.x == 0) {
        int s = 0;
        for (int t = 0; t < NT; ++t) { int c = h[t]; offs[t] = s; s += c; }
        out[0] = 0.0f;
    }
}

// pack atom: (x, y, z, bits(type<<10 | res)); res < 1024, type < 128
__global__ void scatter_k(const float* __restrict__ coords, const int* __restrict__ res,
                          const int* __restrict__ type, int* __restrict__ offs,
                          float4* __restrict__ pc, int N) {
    int i = blockIdx.x * blockDim.x + threadIdx.x;
    if (i >= N) return;
    int t = type[i];
    int p = atomicAdd(&offs[t], 1);
    pc[p] = make_float4(coords[3 * i], coords[3 * i + 1], coords[3 * i + 2],
                        __int_as_float((t << 10) | res[i]));
}

// ---------------- tile body ----------------
// j atom fetched via readfirstlane'd (wave-uniform) index -> scalar load s_load_dwordx4,
// decode on SALU, zero VALU/LDS cost for j. LDS holds the block's sub-LUT, built
// directly from pot (float2 = (e[d], e[min(d+1,27)]), rows padded to stride 32).
// DIAG=false: strict upper-triangle off-diagonal tile. DIAG=true: diagonal tile.
template <bool DIAG>
__device__ __forceinline__ void tile_body(int k,
                                          const float4* __restrict__ pc,
                                          const float* __restrict__ pot,
                                          float* __restrict__ out, int T,
                                          float2* sublut, float* wsum) {
    int r, c;
    if (DIAG) {
        r = k; c = k;
    } else {
        // strict upper triangle: row r has (T-1-r) entries; prefix P(r) = r*(T-1) - r*(r-1)/2
        double tm = 2.0 * T - 1.0;
        double disc = tm * tm - 8.0 * (double)k;
        if (disc < 0.0) disc = 0.0;
        r = (int)((tm - sqrt(disc)) * 0.5);
        if (r < 0) r = 0;
        if (r > T - 2) r = T - 2;
        while (r > 0 && (r * (T - 1) - r * (r - 1) / 2) > k) --r;
        while (((r + 1) * (T - 1) - (r + 1) * r / 2) <= k) ++r;
        c = r + 1 + (k - (r * (T - 1) - r * (r - 1) / 2));
    }

    int bi = r * TILE, bj = c * TILE;
    int tid  = threadIdx.x;
    int lane = tid & 63;

    // contiguous type windows of the two tiles (atoms sorted by type)
    int tminI = __float_as_int(pc[bi].w) >> 10;
    int tmaxI = __float_as_int(pc[bi + TILE - 1].w) >> 10;
    int tminJ = __float_as_int(pc[bj].w) >> 10;
    int tmaxJ = __float_as_int(pc[bj + TILE - 1].w) >> 10;
    int nI = tmaxI - tminI + 1;
    int nRows = nI * (tmaxJ - tminJ + 1);
    bool useLds = (nRows <= MAXR);          // block-uniform
    int nI32 = nI << 5;

    if (useLds) {
        int tot = nRows << 5;
        for (int x = tid; x < tot; x += 256) {
            int u = x >> 5, d = x & 31;
            int cjl = u / nI, cil = u - cjl * nI;
            float e0 = 0.f, e1 = 0.f;
            if (d < BINS) {
                int base = (tminJ + cjl) * NTB + (tminI + cil) * BINS;
                e0 = pot[base + d];
                e1 = pot[base + ((d < BINS - 1) ? d + 1 : d)];
            }
            sublut[x] = make_float2(e0, e1);
        }
    }

    // each thread owns TWO i atoms (lane, lane+64) and 32 j's at stride 4
    int i0 = lane;
    int i1 = lane + 64;
    float4 ciA = pc[bi + i0];
    float4 ciB = pc[bi + i1];
    int wA = __float_as_int(ciA.w);
    int wB = __float_as_int(ciB.w);
    int iresA = wA & 1023;
    int iresB = wB & 1023;
    int rowA, rowB;    // LDS path: (ti-tminI)*32 element offset; global path: ti*BINS
    if (useLds) { rowA = ((wA >> 10) - tminI) << 5; rowB = ((wB >> 10) - tminI) << 5; }
    else        { rowA = (wA >> 10) * BINS;         rowB = (wB >> 10) * BINS; }
    __syncthreads();

    float a0 = 0.f, a1 = 0.f, a2 = 0.f, a3 = 0.f;
    float b0 = 0.f, b1 = 0.f, b2 = 0.f, b3 = 0.f;
    int jj0 = tid >> 6;   // wave id 0..3 — wave-uniform

#define PAIR_LDS(CI, IRES, ROW, IEFF, ACC) do {                        \
    float dx = CI.x - jx, dy = CI.y - jy, dz = CI.z - jz;              \
    float d2 = fmaf(dx, dx, fmaf(dy, dy, dz * dz));                    \
    int  sep = abs(IRES - jres);                                       \
    bool v = (sep > 2) & (d2 < 19.6f * 19.6f);                         \
    if (DIAG) v = v & (J > IEFF);                                      \
    float ds    = __builtin_amdgcn_sqrtf(d2) * (1.0f / 0.7f);          \
    float dsc   = fminf(ds, 31.0f);                                    \
    int   d0    = (int)dsc;                                            \
    float alpha = ds - (float)d0;                                      \
    float2 e = sublut[jrow + ROW + d0];                                \
    float en = fmaf(alpha, e.y - e.x, e.x);                            \
    ACC = fmaf(v ? 1.0f : 0.0f, en, ACC);                              \
} while (0)

#define PAIR_GBL(CI, IRES, ROW, IEFF, ACC) do {                        \
    float dx = CI.x - jx, dy = CI.y - jy, dz = CI.z - jz;              \
    float d2 = fmaf(dx, dx, fmaf(dy, dy, dz * dz));                    \
    int  sep = abs(IRES - jres);                                       \
    bool v = (sep > 2) & (d2 < 19.6f * 19.6f);                         \
    if (DIAG) v = v & (J > IEFF);                                      \
    float ds    = __builtin_amdgcn_sqrtf(d2) * (1.0f / 0.7f);          \
    float dsc   = fminf(ds, 27.0f);                                    \
    int   d0    = (int)dsc;                                            \
    float alpha = ds - (float)d0;                                      \
    int  idx = tjb + ROW + d0;                                         \
    float e0 = pot[idx];                                               \
    float e1 = pot[idx + ((d0 < 27) ? 1 : 0)];                         \
    float en = fmaf(alpha, e1 - e0, e0);                               \
    ACC = fmaf(v ? 1.0f : 0.0f, en, ACC);                              \
} while (0)

    if (useLds) {
#define STEP2L(OFF, AA, AB) do {                                       \
    const int J  = jj0 + (OFF);                                        \
    int Ju = __builtin_amdgcn_readfirstlane(bj + J);                   \
    float4 cj = pc[Ju];                                                \
    float jx = cj.x, jy = cj.y, jz = cj.z;                             \
    int   wj = __float_as_int(cj.w);                                   \
    int jres = wj & 1023;                                              \
    int jrow = ((wj >> 10) - tminJ) * nI32;                            \
    PAIR_LDS(ciA, iresA, rowA, i0, AA);                                \
    PAIR_LDS(ciB, iresB, rowB, i1, AB);                                \
} while (0)
        #pragma unroll
        for (int s = 0; s < 4; ++s) {
            int base = 32 * s;
            STEP2L(base + 0,  a0, b0);
            STEP2L(base + 4,  a1, b1);
            STEP2L(base + 8,  a2, b2);
            STEP2L(base + 12, a3, b3);
            STEP2L(base + 16, a0, b0);
            STEP2L(base + 20, a1, b1);
            STEP2L(base + 24, a2, b2);
            STEP2L(base + 28, a3, b3);
        }
#undef STEP2L
    } else {
#define STEP2G(OFF, AA, AB) do {                                       \
    const int J  = jj0 + (OFF);                                        \
    int Ju = __builtin_amdgcn_readfirstlane(bj + J);                   \
    float4 cj = pc[Ju];                                                \
    float jx = cj.x, jy = cj.y, jz = cj.z;                             \
    int   wj = __float_as_int(cj.w);                                   \
    int jres = wj & 1023;                                              \
    int tjb  = (wj >> 10) * NTB;                                       \
    PAIR_GBL(ciA, iresA, rowA, i0, AA);                                \
    PAIR_GBL(ciB, iresB, rowB, i1, AB);                                \
} while (0)
        #pragma unroll
        for (int s = 0; s < 4; ++s) {
            int base = 32 * s;
            STEP2G(base + 0,  a0, b0);
            STEP2G(base + 4,  a1, b1);
            STEP2G(base + 8,  a2, b2);
            STEP2G(base + 12, a3, b3);
            STEP2G(base + 16, a0, b0);
            STEP2G(base + 20, a1, b1);
            STEP2G(base + 24, a2, b2);
            STEP2G(base + 28, a3, b3);
        }
#undef STEP2G
    }
#undef PAIR_LDS
#undef PAIR_GBL

    float acc = ((a0 + a1) + (a2 + a3)) + ((b0 + b1) + (b2 + b3));
    for (int off = 32; off > 0; off >>= 1)
        acc += __shfl_down(acc, off, 64);
    if ((tid & 63) == 0) wsum[tid >> 6] = acc;
    __syncthreads();
    if (tid == 0) atomicAdd(out, (wsum[0] + wsum[1]) + (wsum[2] + wsum[3]));
}

// ---------------- unified pair kernel: blocks [0,nOff) = off-diag, [nOff,nOff+T) = diag ----------------
__global__ __launch_bounds__(256) void dfire_pairs_all(
    const float4* __restrict__ pc,
    const float* __restrict__ pot,
    float* __restrict__ out, int T, int nOff) {

    __shared__ float2 sublut[MAXR * 32];
    __shared__ float  wsum[4];

    int k = blockIdx.x;
    if (k < nOff) tile_body<false>(k, pc, pot, out, T, sublut, wsum);
    else          tile_body<true >(k - nOff, pc, pot, out, T, sublut, wsum);
}

// ---------------- fallback (ws too small): unsorted, direct pot reads, atomics ----------------
__global__ __launch_bounds__(256) void dfire_pairs_fb(
    const float* __restrict__ coords, const int* __restrict__ res,
    const int* __restrict__ type, const float* __restrict__ pot,
    float* __restrict__ out, int T) {

    __shared__ float jx[TILE], jy[TILE], jz[TILE];
    __shared__ int   jres[TILE], jtype[TILE];

    int k = blockIdx.x;
    int r = (int)((2.0 * T + 1.0 - sqrt((2.0 * T + 1.0) * (2.0 * T + 1.0) - 8.0 * (double)k)) * 0.5);
    if (r < 0) r = 0;
    if (r > T - 1) r = T - 1;
    while (r > 0 && (r * T - r * (r - 1) / 2) > k) --r;
    while (((r + 1) * T - (r + 1) * r / 2) <= k) ++r;
    int c = r + (k - (r * T - r * (r - 1) / 2));

    int bi = r * TILE, bj = c * TILE;
    int tid = threadIdx.x;
    if (tid < TILE) {
        int gj = bj + tid;
        jx[tid] = coords[3 * gj]; jy[tid] = coords[3 * gj + 1]; jz[tid] = coords[3 * gj + 2];
        jres[tid] = res[gj]; jtype[tid] = type[gj];
    }
    int ii = tid & (TILE - 1);
    int gi = bi + ii;
    float ix = coords[3 * gi], iy = coords[3 * gi + 1], iz = coords[3 * gi + 2];
    int ires = res[gi], it = type[gi];
    int ii_eff = (bi == bj) ? ii : -1;
    __syncthreads();

    float acc = 0.f;
    int jj = tid >> 7;
    for (int s = 0; s < TILE / 2; ++s, jj += 2) {
        float dx = ix - jx[jj], dy = iy - jy[jj], dz = iz - jz[jj];
        float d2 = dx * dx + dy * dy + dz * dz;
        float dist = sqrtf(d2) + 1e-8f;
        int sep = abs(ires - jres[jj]);
        bool v = (sep > 2) & (dist < 19.6f) & (jj > ii_eff);
        if (v) {
            float ds = dist * (1.0f / 0.7f);
            int d0 = (int)fminf(ds, 27.0f);
            int d1 = (d0 + 1 < BINS) ? d0 + 1 : BINS - 1;
            float alpha = ds - (float)d0;
            int row = (jtype[jj] * NT + it) * BINS;
            float e0 = pot[row + d0], e1 = pot[row + d1];
            acc += e0 + alpha * (e1 - e0);
        }
    }
    for (int off = 32; off > 0; off >>= 1)
        acc += __shfl_down(acc, off, 64);
    if ((tid & 63) == 0) atomicAdd(out, acc);
}

extern "C" void kernel_launch(void* const* d_in, const int* in_sizes, int n_in,
                              void* d_out, int out_size, void* d_ws, size_t ws_size,
                              hipStream_t stream) {
    const float* coords = (const float*)d_in[0];
    const float* pot    = (const float*)d_in[1];
    const int*   res    = (const int*)d_in[2];
    const int*   type   = (const int*)d_in[3];
    // d_in[4], d_in[5] (i_idx/j_idx) unused: pairs generated on the fly from triu structure.

    const int N = in_sizes[2];
    const int T = N / TILE;
    const int nblk = T * (T + 1) / 2;

    float* out = (float*)d_out;

    const size_t pcBytes   = (size_t)N * sizeof(float4);
    const size_t offsBytes = 128 * sizeof(int);
    const size_t need = pcBytes + offsBytes;

    if (ws_size >= need) {
        char* w = (char*)d_ws;
        float4* pc   = (float4*)w;   w += pcBytes;
        int*    offs = (int*)w;

        const int nOff = T * (T - 1) / 2;   // off-diagonal tiles
        // 3 launches: hist/scan+out=0 -> scatter -> pairs (off+diag merged, stages sub-LUT from pot)
        hist_k<<<1, 256, 0, stream>>>(type, offs, out, N);
        scatter_k<<<(N + 255) / 256, 256, 0, stream>>>(coords, res, type, offs, pc, N);
        dfire_pairs_all<<<nOff + T, 256, 0, stream>>>(pc, pot, out, T, nOff);
    } else {
        hipMemsetAsync(out, 0, sizeof(float), stream);
        dfire_pairs_fb<<<nblk, 256, 0, stream>>>(coords, res, type, pot, out, T);
    }
}